// Round 7
// baseline (390.482 us; speedup 1.0000x reference)
//
#include <hip/hip_runtime.h>
#include <stdint.h>

// Problem constants (fixed by the reference):
#define Bq      64
#define Nq      256
#define Hq      8
#define DHq     64
#define TOTALq  16384    // B*N
#define NTq     131072   // H*TOTAL
#define Dq      512      // H*DH

typedef __attribute__((ext_vector_type(8))) short short8;
typedef __attribute__((ext_vector_type(4))) float floatx4;

__device__ __forceinline__ unsigned short f2bf(float f) {
    union { float f; unsigned int u; } c; c.f = f;
    unsigned int u = c.u;
    return (unsigned short)((u + 0x7fffu + ((u >> 16) & 1u)) >> 16);
}
__device__ __forceinline__ float bf2f(unsigned short u) {
    union { unsigned int u; float f; } c; c.u = ((unsigned int)u) << 16;
    return c.f;
}

// ---------------------------------------------------------------------------
// pscatter: dense per-sample P scatter (dinv folded in; bit-identical).
// ---------------------------------------------------------------------------
__global__ void pscatter_kernel(const int* __restrict__ srcp, const int* __restrict__ dstp,
                                const int* __restrict__ cnt, float* __restrict__ Pf, int E) {
    int e = blockIdx.x * 256 + threadIdx.x;
    if (e >= E) return;
    int s = srcp[e], d = dstp[e];
    int cs = cnt[s], cd = cnt[d];
    float dvs = (cs > 0) ? rsqrtf((float)cs) : 0.0f;
    float dvd = (cd > 0) ? rsqrtf((float)cd) : 0.0f;
    int g = d >> 8;  // sample index
    atomicAdd(&Pf[((size_t)g << 16) + ((size_t)(d & 255) << 8) + (s & 255)],
              -(dvs * dvd));
}

__global__ void pconv_kernel(const float* __restrict__ Pf, unsigned short* __restrict__ Pb) {
    int i = (blockIdx.x * 256 + threadIdx.x) * 4;
    float4 v = *(const float4*)(Pf + i);
    unsigned int lo = (unsigned int)f2bf(v.x) | ((unsigned int)f2bf(v.y) << 16);
    unsigned int hi = (unsigned int)f2bf(v.z) | ((unsigned int)f2bf(v.w) << 16);
    *(uint2*)(Pb + i) = make_uint2(lo, hi);
}

// ---------------------------------------------------------------------------
// Heterogeneous front kernel (unchanged from r6 — passed).
// ---------------------------------------------------------------------------
__global__ __launch_bounds__(512, 1)
void front_kernel(const float* __restrict__ attn,
                  const float* __restrict__ Wg, const float* __restrict__ bg,
                  const float* __restrict__ Wlin, const float* __restrict__ blin,
                  float* __restrict__ coeff,
                  const int* __restrict__ dstp, int* __restrict__ cnt, int E,
                  const float* __restrict__ Wcat, unsigned short* __restrict__ Wt2,
                  const float* __restrict__ Wch, float* __restrict__ WchTf,
                  float* __restrict__ Pf) {
    __shared__ floatx4 part[8][64];   // 8 KB
    __shared__ floatx4 dinv4[64];     // 1 KB
    const int bid = blockIdx.x;
    const int tid = threadIdx.x;

    if (bid < 512) {
        const int g = bid;
        const int h = g >> 6;
        const int b = g & 63;
        const float* A = attn + ((size_t)(b * Hq + h)) * (Nq * Nq);
        const int rg = tid >> 6;
        const int cv = tid & 63;
        const float* Ap = A + cv * 4;

        floatx4 regs[32];
        floatx4 s1 = (floatx4){0.f, 0.f, 0.f, 0.f};
#pragma unroll
        for (int r = 0; r < 32; ++r) {
            regs[r] = *(const floatx4*)(Ap + (size_t)(rg * 32 + r) * 256);
            s1 += regs[r];
        }
        part[rg][cv] = s1;
        __syncthreads();

        if (tid < 64) {
            floatx4 cs = part[0][tid];
#pragma unroll
            for (int i = 1; i < 8; ++i) cs += part[i][tid];
            floatx4 dv;
#pragma unroll
            for (int i = 0; i < 4; ++i) dv[i] = rsqrtf(cs[i] + 1.0f);
            dinv4[tid] = dv;
        }
        __syncthreads();

        const float* dsc = (const float*)dinv4;
        floatx4 s2 = (floatx4){0.f, 0.f, 0.f, 0.f};
#pragma unroll
        for (int r = 0; r < 32; ++r)
            s2 += dsc[rg * 32 + r] * regs[r];
        part[rg][cv] = s2;
        __syncthreads();

        if (tid < 64) {
            floatx4 ws = part[0][tid];
#pragma unroll
            for (int i = 1; i < 8; ++i) ws += part[i][tid];
            floatx4 dv = dinv4[tid];
            floatx4 sj = (ws + dv) * dv;

            float wr[4], bgl[4];
#pragma unroll
            for (int c = 0; c < 4; ++c) {
                wr[c]  = Wg[0 * 4 + c] + Wg[1 * 4 + c] + Wg[2 * 4 + c] + Wg[3 * 4 + c];
                bgl[c] = bg[c];
            }
            float v[4];
#pragma unroll
            for (int c = 0; c < 4; ++c) {
                v[c] = tanhf(sj[0] * wr[c] + bgl[c]) + tanhf(sj[1] * wr[c] + bgl[c]) +
                       tanhf(sj[2] * wr[c] + bgl[c]) + tanhf(sj[3] * wr[c] + bgl[c]);
#pragma unroll
                for (int o = 32; o >= 1; o >>= 1) v[c] += __shfl_down(v[c], o, 64);
            }
            float g0 = __shfl(v[0], 0, 64), g1 = __shfl(v[1], 0, 64);
            float g2 = __shfl(v[2], 0, 64), g3 = __shfl(v[3], 0, 64);
            if (tid < 4) {
                float r = blin[tid] + (g0 * Wlin[0 * 4 + tid] + g1 * Wlin[1 * 4 + tid] +
                                       g2 * Wlin[2 * 4 + tid] + g3 * Wlin[3 * 4 + tid]) *
                                          (1.0f / 256.0f);
                coeff[g * 4 + tid] = r;
            }
        }
        return;
    }

    const int nbCnt = (E + 511) >> 9;
    if (bid < 512 + nbCnt) {
        int e = (bid - 512) * 512 + tid;
        if (e < E) atomicAdd(&cnt[dstp[e]], 1);
        return;
    }
    if (bid < 512 + nbCnt + 160) {
        int pb = bid - 512 - nbCnt;
        if (pb < 128) {
            int idx = pb * 512 + tid;
            int col = idx & 511;
            int ktq = idx >> 9;
            const float* src = Wcat + (size_t)(ktq * 8) * 512 + col;
            unsigned int pk[4];
#pragma unroll
            for (int q2 = 0; q2 < 4; ++q2) {
                unsigned short a = f2bf(src[(q2 * 2 + 0) * 512]);
                unsigned short b = f2bf(src[(q2 * 2 + 1) * 512]);
                pk[q2] = (unsigned int)a | ((unsigned int)b << 16);
            }
            *(uint4*)(Wt2 + (size_t)idx * 8) = make_uint4(pk[0], pk[1], pk[2], pk[3]);
        } else {
            int idx = (pb - 128) * 512 + tid;
            int k = idx >> 12, rem = idx & 4095;
            int n = rem >> 6, j = rem & 63;
            WchTf[idx] = Wch[(k << 12) + (j << 6) + n];
        }
        return;
    }
    {
        int zb = bid - 512 - nbCnt - 160;
        size_t i = ((size_t)zb * 512 + tid) * 4;
        *(float4*)(Pf + i) = make_float4(0.f, 0.f, 0.f, 0.f);
    }
}

// ---------------------------------------------------------------------------
// FUSED Chebyshev recursion + filter.
// r7: explicit double-buffered P-fragment prefetch (paA/paB, issued 2 kt ahead;
// first two issued before the filt MFMA cluster so filt covers their latency).
// curp register array deleted — "current T" re-read from cm at rotate (still
// resident; each thread touches only its own slot). VGPR-neutral vs r6.
// ---------------------------------------------------------------------------
__global__ __launch_bounds__(512, 4)
void cheb_fused(const unsigned short* __restrict__ Pb, const float* __restrict__ oeh,
                const float* __restrict__ WchTf, const float* __restrict__ coeff,
                const float* __restrict__ bch, unsigned short* __restrict__ filtb) {
    extern __shared__ unsigned char sm[];
    unsigned short* cm = (unsigned short*)sm;            // [64][256] swizzled, 32 KB
    unsigned short* rm = (unsigned short*)(sm + 32768);  // [256][64] swizzled, 32 KB
    unsigned short* Wl = (unsigned short*)(sm + 65536);  // [64][72], 9 KB

    const int g = blockIdx.x;
    const int b = (g & 7) * 8 + ((g >> 3) & 7);  // XCD-chunked: same b -> same XCD
    const int h = g >> 6;
    const int tid = threadIdx.x;
    const int lane = tid & 63, wv = tid >> 6;
    const int wr = wv >> 1, wc = wv & 1;
    const int quad = lane >> 4, l15 = lane & 15;

    const unsigned short* Pbase = Pb + ((size_t)b << 16);
    // per-thread P row pointer: row = wr*64 + l15 (+ rt*16), col base quad*8
    const unsigned short* Prow = Pbase + (size_t)(wr * 64 + l15) * 256 + quad * 8;
    const float* cf = coeff + (h * 64 + b) * 4;

    // ---- stage X0 (cm + rm) and W0 ----
    {
        const int sn = tid >> 1;
        const int sh = (tid & 1) * 32;
        const float* sp = oeh + (size_t)(b * 256 + sn) * 512 + h * 64 + sh;
        unsigned int pk[16];
#pragma unroll
        for (int j = 0; j < 8; ++j) {
            float4 v = *(const float4*)(sp + j * 4);
            pk[2 * j]     = (unsigned)f2bf(v.x) | ((unsigned)f2bf(v.y) << 16);
            pk[2 * j + 1] = (unsigned)f2bf(v.z) | ((unsigned)f2bf(v.w) << 16);
        }
#pragma unroll
        for (int jj = 0; jj < 4; ++jj)
            *(uint4*)(rm + sn * 64 + ((((sh >> 3) + jj) ^ (sn & 7)) << 3)) =
                make_uint4(pk[4 * jj], pk[4 * jj + 1], pk[4 * jj + 2], pk[4 * jj + 3]);
#pragma unroll
        for (int e = 0; e < 32; ++e) {
            int c = sh + e;
            unsigned short v =
                (unsigned short)((e & 1) ? (pk[e >> 1] >> 16) : (pk[e >> 1] & 0xffffu));
            cm[c * 256 + (((sn >> 3) ^ (c & 31)) << 3) + (sn & 7)] = v;
        }
        float ck = cf[0];
        int r = tid >> 3, su = tid & 7;
        const float* wp = WchTf + r * 64 + su * 8;
        float4 w0 = *(const float4*)wp, w1 = *(const float4*)(wp + 4);
        *(uint4*)(Wl + r * 72 + su * 8) = make_uint4(
            (unsigned)f2bf(w0.x * ck) | ((unsigned)f2bf(w0.y * ck) << 16),
            (unsigned)f2bf(w0.z * ck) | ((unsigned)f2bf(w0.w * ck) << 16),
            (unsigned)f2bf(w1.x * ck) | ((unsigned)f2bf(w1.y * ck) << 16),
            (unsigned)f2bf(w1.z * ck) | ((unsigned)f2bf(w1.w * ck) << 16));
    }
    __syncthreads();

    unsigned int prvp[4][2][2];
#pragma unroll
    for (int rt = 0; rt < 4; ++rt)
#pragma unroll
        for (int ct = 0; ct < 2; ++ct)
#pragma unroll
            for (int p = 0; p < 2; ++p) prvp[rt][ct][p] = 0u;

    floatx4 accf[4][2];
#pragma unroll
    for (int rt = 0; rt < 4; ++rt)
#pragma unroll
        for (int ct = 0; ct < 2; ++ct) accf[rt][ct] = (floatx4){0.f, 0.f, 0.f, 0.f};

#pragma unroll
    for (int k = 0; k < 4; ++k) {
        // ---- pre-issue P fragments for kt=0,1 (covered by filt below) ----
        short8 paA[4], paB[4];
        if (k < 3) {
#pragma unroll
            for (int rt = 0; rt < 4; ++rt)
                paA[rt] = *(const short8*)(Prow + rt * 16 * 256);
#pragma unroll
            for (int rt = 0; rt < 4; ++rt)
                paB[rt] = *(const short8*)(Prow + rt * 16 * 256 + 32);
        }
        // ---- filt_k: accf += T_k(rm) @ (ck*W_k)(Wl) ----
#pragma unroll
        for (int kk = 0; kk < 2; ++kk) {
            short8 af[4], bfw[2];
#pragma unroll
            for (int rt = 0; rt < 4; ++rt) {
                int row = wr * 64 + rt * 16 + l15;
                af[rt] = *(const short8*)(rm + row * 64 + (((kk * 4 + quad) ^ (row & 7)) << 3));
            }
#pragma unroll
            for (int ct = 0; ct < 2; ++ct) {
                int oc = wc * 32 + ct * 16 + l15;
                bfw[ct] = *(const short8*)(Wl + oc * 72 + kk * 32 + quad * 8);
            }
#pragma unroll
            for (int rt = 0; rt < 4; ++rt)
#pragma unroll
                for (int ct = 0; ct < 2; ++ct)
                    accf[rt][ct] = __builtin_amdgcn_mfma_f32_16x16x32_bf16(
                        af[rt], bfw[ct], accf[rt][ct], 0, 0, 0);
        }
        if (k < 3) {
            // ---- prop: accp = P @ T_k (pipelined P prefetch, B from cm) ----
            floatx4 accp[4][2];
#pragma unroll
            for (int rt = 0; rt < 4; ++rt)
#pragma unroll
                for (int ct = 0; ct < 2; ++ct) accp[rt][ct] = (floatx4){0.f, 0.f, 0.f, 0.f};

#define PSTEP(KT, CUR)                                                              \
    do {                                                                            \
        short8 bp_[2];                                                              \
        _Pragma("unroll")                                                           \
        for (int ct = 0; ct < 2; ++ct) {                                            \
            int c = wc * 32 + ct * 16 + l15;                                        \
            bp_[ct] = *(const short8*)(cm + c * 256 +                               \
                                       ((((KT) * 4 + quad) ^ (c & 31)) << 3));      \
        }                                                                           \
        _Pragma("unroll")                                                           \
        for (int rt = 0; rt < 4; ++rt)                                              \
            _Pragma("unroll")                                                       \
            for (int ct = 0; ct < 2; ++ct)                                          \
                accp[rt][ct] = __builtin_amdgcn_mfma_f32_16x16x32_bf16(             \
                    CUR[rt], bp_[ct], accp[rt][ct], 0, 0, 0);                       \
        if ((KT) + 2 < 8) {                                                         \
            _Pragma("unroll")                                                       \
            for (int rt = 0; rt < 4; ++rt)                                          \
                CUR[rt] = *(const short8*)(Prow + rt * 16 * 256 + ((KT) + 2) * 32); \
        }                                                                           \
    } while (0)

            PSTEP(0, paA); PSTEP(1, paB);
            PSTEP(2, paA); PSTEP(3, paB);
            PSTEP(4, paA); PSTEP(5, paB);
            PSTEP(6, paA); PSTEP(7, paB);
#undef PSTEP

            __syncthreads();  // all reads of cm/rm/Wl done
            // ---- write T_{k+1}; rotate (cur re-read from cm); stage W_{k+1} ----
#pragma unroll
            for (int rt = 0; rt < 4; ++rt)
#pragma unroll
                for (int ct = 0; ct < 2; ++ct)
#pragma unroll
                    for (int p = 0; p < 2; ++p) {
                        int m = wr * 64 + rt * 16 + quad * 4 + 2 * p;
                        int c = wc * 32 + ct * 16 + l15;
                        unsigned int* cmSlot =
                            (unsigned int*)(cm + c * 256 + (((m >> 3) ^ (c & 31)) << 3) +
                                            (m & 7));
                        unsigned cur = *cmSlot;
                        float a0 = accp[rt][ct][2 * p], a1 = accp[rt][ct][2 * p + 1];
                        if (k > 0) {
                            unsigned pv = prvp[rt][ct][p];
                            a0 = 2.0f * a0 - bf2f((unsigned short)(pv & 0xffffu));
                            a1 = 2.0f * a1 - bf2f((unsigned short)(pv >> 16));
                        }
                        unsigned nv = (unsigned)f2bf(a0) | ((unsigned)f2bf(a1) << 16);
                        prvp[rt][ct][p] = cur;
                        if (k < 2)  // T3 never used as prop B-operand
                            *cmSlot = nv;
                        rm[m * 64 + (((c >> 3) ^ (m & 7)) << 3) + (c & 7)] =
                            (unsigned short)(nv & 0xffffu);
                        rm[(m + 1) * 64 + (((c >> 3) ^ ((m + 1) & 7)) << 3) + (c & 7)] =
                            (unsigned short)(nv >> 16);
                    }
            {
                float ck = cf[k + 1];
                int r = tid >> 3, su = tid & 7;
                const float* wp = WchTf + (k + 1) * 4096 + r * 64 + su * 8;
                float4 w0 = *(const float4*)wp, w1 = *(const float4*)(wp + 4);
                *(uint4*)(Wl + r * 72 + su * 8) = make_uint4(
                    (unsigned)f2bf(w0.x * ck) | ((unsigned)f2bf(w0.y * ck) << 16),
                    (unsigned)f2bf(w0.z * ck) | ((unsigned)f2bf(w0.w * ck) << 16),
                    (unsigned)f2bf(w1.x * ck) | ((unsigned)f2bf(w1.y * ck) << 16),
                    (unsigned)f2bf(w1.z * ck) | ((unsigned)f2bf(w1.w * ck) << 16));
            }
            __syncthreads();
        }
    }

    // ---- epilogue: filtb[(n*B+b)*512 + h*64 + c] = bf16(accf + b_cheb) ----
    float bias[2];
#pragma unroll
    for (int ct = 0; ct < 2; ++ct) bias[ct] = bch[wc * 32 + ct * 16 + l15];
#pragma unroll
    for (int rt = 0; rt < 4; ++rt)
#pragma unroll
        for (int ct = 0; ct < 2; ++ct) {
            int c = wc * 32 + ct * 16 + l15;
#pragma unroll
            for (int i = 0; i < 4; ++i) {
                int m = wr * 64 + rt * 16 + quad * 4 + i;
                filtb[((size_t)m * 64 + b) * 512 + h * 64 + c] =
                    f2bf(accf[rt][ct][i] + bias[ct]);
            }
        }
}

// ---------------------------------------------------------------------------
// MFMA GEMM (M=16384, K=1024, N=512) + fused LayerNorm (unchanged from r5/r6).
// ---------------------------------------------------------------------------
__global__ __launch_bounds__(512, 2)
void gemm_ln_mfma(const float* __restrict__ outp, const unsigned short* __restrict__ filtb,
                  const unsigned short* __restrict__ Wt2, const float* __restrict__ bcat,
                  const float* __restrict__ gamma, const float* __restrict__ beta,
                  float* __restrict__ out) {
    extern __shared__ unsigned char smc[];
    unsigned short* A_lds0 = (unsigned short*)smc;           // 4 KB
    unsigned short* A_lds1 = (unsigned short*)(smc + 4096);  // 4 KB
    float* ep = (float*)smc;                                 // 64 KB epilogue overlay

    const int tid = threadIdx.x;
    const int lane = tid & 63;
    const int wv = tid >> 6;
    const int quad = lane >> 4;
    const int l15 = lane & 15;
    const int r0 = blockIdx.x * 64;

    const int s_row = tid >> 3;
    const int s_sub = tid & 7;
    const int s_q   = s_sub >> 1;
    const int s_e   = (s_sub & 1) * 4;

    const size_t boff = (size_t)(quad * 512 + wv * 64 + l15) * 8;

    floatx4 acc[4][4];
#pragma unroll
    for (int rt = 0; rt < 4; ++rt)
#pragma unroll
        for (int ct = 0; ct < 4; ++ct) acc[rt][ct] = (floatx4){0.f, 0.f, 0.f, 0.f};

    short8 bA[4], bB[4];
    float4 avX_f, avY_f;
    uint2  avX_b, avY_b;

    {
#pragma unroll
        for (int ct = 0; ct < 4; ++ct)
            bA[ct] = *(const short8*)(Wt2 + boff + ct * 128);
#pragma unroll
        for (int ct = 0; ct < 4; ++ct)
            bB[ct] = *(const short8*)(Wt2 + (size_t)16384 + boff + ct * 128);
        float4 av = *(const float4*)(outp + (size_t)(r0 + s_row) * 512 + s_sub * 4);
        avY_f = *(const float4*)(outp + (size_t)(r0 + s_row) * 512 + 32 + s_sub * 4);
        uint2 ap;
        ap.x = (unsigned int)f2bf(av.x) | ((unsigned int)f2bf(av.y) << 16);
        ap.y = (unsigned int)f2bf(av.z) | ((unsigned int)f2bf(av.w) << 16);
        *(uint2*)(A_lds0 + (s_q * 64 + s_row) * 8 + s_e) = ap;
        __syncthreads();
    }

#define GSTEP(KT, BCUR, AC, AN, AVCF, AVCB, AVNF, AVNB)                             \
    do {                                                                            \
        const int kt_ = (KT);                                                       \
        if (kt_ <= 29) {                                                            \
            const int kc2_ = (kt_ + 2) * 32;                                        \
            if (kc2_ < 512)                                                         \
                AVNF = *(const float4*)(outp + (size_t)(r0 + s_row) * 512 +         \
                                        kc2_ + s_sub * 4);                          \
            else                                                                    \
                AVNB = *(const uint2*)(filtb + (size_t)(r0 + s_row) * 512 +         \
                                       (kc2_ - 512) + s_sub * 4);                   \
        }                                                                           \
        short8 af_[4];                                                              \
        _Pragma("unroll")                                                           \
        for (int rt = 0; rt < 4; ++rt)                                              \
            af_[rt] = *(const short8*)(AC + (quad * 64 + rt * 16 + l15) * 8);       \
        _Pragma("unroll")                                                           \
        for (int rt = 0; rt < 4; ++rt)                                              \
            _Pragma("unroll")                                                       \
            for (int ct = 0; ct < 4; ++ct)                                          \
                acc[rt][ct] = __builtin_amdgcn_mfma_f32_16x16x32_bf16(              \
                    af_[rt], BCUR[ct], acc[rt][ct], 0, 0, 0);                       \
        if (kt_ <= 29) {                                                            \
            _Pragma("unroll")                                                       \
            for (int ct = 0; ct < 4; ++ct)                                          \
                BCUR[ct] = *(const short8*)(Wt2 + (size_t)(kt_ + 2) * 16384 +       \
                                            boff + ct * 128);                       \
        }                                                                           \
        if (kt_ <= 30) {                                                            \
            uint2 ap_;                                                              \
            if ((kt_ + 1) * 32 < 512) {                                             \
                ap_.x = (unsigned int)f2bf(AVCF.x) | ((unsigned int)f2bf(AVCF.y) << 16); \
                ap_.y = (unsigned int)f2bf(AVCF.z) | ((unsigned int)f2bf(AVCF.w) << 16); \
            } else {                                                                \
                ap_ = AVCB;                                                         \
            }                                                                       \
            *(uint2*)(AN + (s_q * 64 + s_row) * 8 + s_e) = ap_;                     \
        }                                                                           \
        asm volatile("s_waitcnt lgkmcnt(0)" ::: "memory");                          \
        __builtin_amdgcn_s_barrier();                                               \
        __builtin_amdgcn_sched_barrier(0);                                          \
    } while (0)

    for (int kt2 = 0; kt2 < 16; ++kt2) {
        GSTEP(2 * kt2,     bA, A_lds0, A_lds1, avY_f, avY_b, avX_f, avX_b);
        GSTEP(2 * kt2 + 1, bB, A_lds1, A_lds0, avX_f, avX_b, avY_f, avY_b);
    }
#undef GSTEP

    float gg[8], bb[8];
#pragma unroll
    for (int i = 0; i < 8; ++i) { gg[i] = gamma[i * 64 + lane]; bb[i] = beta[i * 64 + lane]; }
    float bc[4];
#pragma unroll
    for (int ct = 0; ct < 4; ++ct) bc[ct] = bcat[wv * 64 + ct * 16 + l15];

    for (int half = 0; half < 2; ++half) {
        __syncthreads();
#pragma unroll
        for (int rt2 = 0; rt2 < 2; ++rt2) {
            const int rt = half * 2 + rt2;
#pragma unroll
            for (int ct = 0; ct < 4; ++ct) {
                const int col = wv * 64 + ct * 16 + l15;
#pragma unroll
                for (int i = 0; i < 4; ++i) {
                    const int row_l = rt2 * 16 + quad * 4 + i;
                    ep[row_l * 512 + col] = acc[rt][ct][i] + bc[ct];
                }
            }
        }
        __syncthreads();
#pragma unroll
        for (int m4 = 0; m4 < 4; ++m4) {
            const int m = wv * 4 + m4;
            float s = 0.0f, ss = 0.0f;
#pragma unroll
            for (int i = 0; i < 8; ++i) {
                float v = ep[m * 512 + i * 64 + lane];
                s += v; ss += v * v;
            }
#pragma unroll
            for (int o = 32; o >= 1; o >>= 1) {
                s += __shfl_down(s, o, 64);
                ss += __shfl_down(ss, o, 64);
            }
            s = __shfl(s, 0, 64);
            ss = __shfl(ss, 0, 64);
            const float mu = s * (1.0f / 512.0f);
            const float var = ss * (1.0f / 512.0f) - mu * mu;
            const float rs = rsqrtf(var + 1e-5f);
            const int r = r0 + half * 32 + m;
#pragma unroll
            for (int i = 0; i < 8; ++i) {
                const int d = i * 64 + lane;
                out[(size_t)r * 512 + d] = (ep[m * 512 + d] - mu) * rs * gg[i] + bb[i];
            }
        }
    }
}

// ---------------------------------------------------------------------------
// Launch
// ---------------------------------------------------------------------------
extern "C" void kernel_launch(void* const* d_in, const int* in_sizes, int n_in,
                              void* d_out, int out_size, void* d_ws, size_t ws_size,
                              hipStream_t stream) {
    const float* output       = (const float*)d_in[0];
    const float* attn         = (const float*)d_in[1];
    const float* oeh          = (const float*)d_in[2];
    const int*   edge_index   = (const int*)d_in[3];
    const float* W_gcn        = (const float*)d_in[6];
    const float* b_gcn        = (const float*)d_in[7];
    const float* W_lin        = (const float*)d_in[8];
    const float* b_lin        = (const float*)d_in[9];
    const float* W_cheb       = (const float*)d_in[10];
    const float* b_cheb       = (const float*)d_in[11];
    const float* W_cat        = (const float*)d_in[12];
    const float* b_cat        = (const float*)d_in[13];
    const float* gamma        = (const float*)d_in[14];
    const float* beta         = (const float*)d_in[15];
    float* out = (float*)d_out;

    const int E = in_sizes[3] / 2;
    const int* srcp = edge_index;
    const int* dstp = edge_index + E;

    uint8_t* ws = (uint8_t*)d_ws;
    size_t cur = 0;
    auto alloc = [&](size_t bytes) -> void* {
        void* p = ws + cur;
        cur += (bytes + 255) & ~(size_t)255;
        return p;
    };
    int*   cnt     = (int*)alloc(TOTALq * sizeof(int));
    float* Pf      = (float*)alloc((size_t)64 * 65536 * sizeof(float));     // 16.8 MB
    unsigned short* Pb   = (unsigned short*)alloc((size_t)64 * 65536 * 2);  //  8.4 MB
    float* coeff   = (float*)alloc(512 * 4 * sizeof(float));
    float* WchTf   = (float*)alloc(4 * 64 * 64 * sizeof(float));
    unsigned short* Wt2  = (unsigned short*)alloc((size_t)Dq * 1024 * 2);
    unsigned short* filtb = (unsigned short*)alloc((size_t)TOTALq * Dq * 2);
    (void)ws_size; (void)n_in; (void)out_size;

    hipMemsetAsync(cnt, 0, TOTALq * sizeof(int), stream);

    const int nbCnt = (E + 511) / 512;
    const int frontGrid = 512 + nbCnt + 160 + 2048;
    front_kernel<<<frontGrid, 512, 0, stream>>>(attn, W_gcn, b_gcn, W_lin, b_lin, coeff,
                                                dstp, cnt, E, W_cat, Wt2, W_cheb, WchTf,
                                                Pf);

    pscatter_kernel<<<(E + 255) / 256, 256, 0, stream>>>(srcp, dstp, cnt, Pf, E);
    pconv_kernel<<<4096, 256, 0, stream>>>(Pf, Pb);

    cheb_fused<<<512, 512, 74752, stream>>>(Pb, oeh, WchTf, coeff, b_cheb, filtb);

    gemm_ln_mfma<<<TOTALq / 64, 512, 65536, stream>>>(output, filtb, Wt2, b_cat,
                                                      gamma, beta, out);
}